// Round 13
// baseline (31.034 us; speedup 1.0000x reference)
//
#include <hip/hip_runtime.h>

// T_lv2: out[0..4718591]        = fold(gather(unfold(ref_lv2,3,1,1)))/9  [4,128,96,96]
// T_lv1: out[4718592..14155775] = fold(gather(unfold(ref_lv1,6,2,2)))/9  [4,64,192,192]
//
// R11 (fixed): tap table (R6) + 16B/8-value bf16 cells (R3) : each random
// ds_read_b128 serves 8 outputs (halves gather instruction count vs R10).
// 256 blocks x 1024 thr, 147.5KB LDS (1 block/CU):
//  - lv1 (bid<128):   (b, parity q, 4-ch grp); cell(ysh,xsh) word k = ch k {x0,x1}
//  - lv2 (bid>=128):  (b, 8-ch grp, pos half); cell(ys,xs) word k = {c2k,c2k+1}
// Table: tabA[b][u]=uint4 (taps 0..7 as 8xu16 cell idx), tabB=tap 8; ZCELL
// sentinel -> zeroed cell. 1/9 applied once at the end. cvt_pk_bf16 staging.

typedef float f2 __attribute__((ext_vector_type(2)));
typedef float f4 __attribute__((ext_vector_type(4)));

#define NINE_INV (1.0f / 9.0f)
#define ZCELL 9216u

__device__ __forceinline__ unsigned cvt_pk_bf16(float a, float b) {
    unsigned r;
    asm("v_cvt_pk_bf16_f32 %0, %1, %2" : "=v"(r) : "v"(a), "v"(b));
    return r;   // lo16 = bf16(a), hi16 = bf16(b), RNE
}
__device__ __forceinline__ f2 up2(unsigned w) {
    f2 r;
    r.x = __builtin_bit_cast(float, w << 16);
    r.y = __builtin_bit_cast(float, w & 0xffff0000u);
    return r;
}
template <typename T> __device__ __forceinline__ T ntload(const T* p) {
    return __builtin_nontemporal_load(p);
}
template <typename T> __device__ __forceinline__ void ntstore(T* p, T v) {
    __builtin_nontemporal_store(v, p);
}

// Build the packed tap table: tabA[g] = taps 0..7 (8 x u16 cell idx), tabB[g] = tap 8.
__global__ __launch_bounds__(256) void table_kernel(
    const int* __restrict__ idx, uint4* __restrict__ tabA,
    unsigned short* __restrict__ tabB)
{
    int g = blockIdx.x * 256 + threadIdx.x;       // 0..36863
    int b = g / 9216;
    int u = g - b * 9216;
    const int* idxb = idx + b * 9216;
    int r = u / 96, t = u - 96 * r;
    unsigned e[9];
#pragma unroll
    for (int i = 0; i < 3; ++i) {
        int oy = r - 1 + i;
        bool oyv = (unsigned)oy < 96u;
#pragma unroll
        for (int j = 0; j < 3; ++j) {
            int ox = t - 1 + j;
            bool pv = oyv & ((unsigned)ox < 96u);
            int jv = idxb[pv ? oy * 96 + ox : 0];
            int jy = jv / 96, jx = jv - 96 * jy;
            int ysh = jy + 1 - i, xsh = jx + 1 - j;
            bool sv = pv & ((unsigned)ysh < 96u) & ((unsigned)xsh < 96u);
            e[i * 3 + j] = sv ? (unsigned)(ysh * 96 + xsh) : ZCELL;
        }
    }
    uint4 w;
    w.x = e[0] | (e[1] << 16);
    w.y = e[2] | (e[3] << 16);
    w.z = e[4] | (e[5] << 16);
    w.w = e[6] | (e[7] << 16);
    tabA[g] = w;
    tabB[g] = (unsigned short)e[8];
}

template <bool TAB>
__global__ __launch_bounds__(1024, 4) void transfer_kernel(
    const int* __restrict__ idx,      // [4, 9216]
    const float* __restrict__ ref1,   // [4,64,192,192]
    const float* __restrict__ ref2,   // [4,128,96,96]
    const uint4* __restrict__ tabA,   // [4][9216] taps 0..7
    const unsigned short* __restrict__ tabB, // [4][9216] tap 8
    float* __restrict__ out)
{
    __shared__ __align__(16) unsigned s4[36868];   // 9217 cells x 4 words (16B)
    const int tid = threadIdx.x;
    const int bid = blockIdx.x;

    if (tid < 4) s4[36864 + tid] = 0;              // zero cell

    const int b = bid & 3;
    const uint4* tA = tabA + b * 9216;
    const unsigned short* tB = tabB + b * 9216;
    const int* idxb = idx + b * 9216;
    const f2 nv = {NINE_INV, NINE_INV};

    // Fallback: compute one position's packed taps inline.
    auto make_cells = [&](int u, uint4& A, unsigned& B) {
        int r = u / 96, t = u - 96 * r;
        unsigned e[9];
#pragma unroll
        for (int i = 0; i < 3; ++i) {
            int oy = r - 1 + i;
            bool oyv = (unsigned)oy < 96u;
#pragma unroll
            for (int j = 0; j < 3; ++j) {
                int ox = t - 1 + j;
                bool pv = oyv & ((unsigned)ox < 96u);
                int jv = idxb[pv ? oy * 96 + ox : 0];
                int jy = jv / 96, jx = jv - 96 * jy;
                int ysh = jy + 1 - i, xsh = jx + 1 - j;
                bool sv = pv & ((unsigned)ysh < 96u) & ((unsigned)xsh < 96u);
                e[i * 3 + j] = sv ? (unsigned)(ysh * 96 + xsh) : ZCELL;
            }
        }
        A.x = e[0] | (e[1] << 16); A.y = e[2] | (e[3] << 16);
        A.z = e[4] | (e[5] << 16); A.w = e[6] | (e[7] << 16);
        B = e[8];
    };

    // 9 random ds_read_b128 taps -> 4 f2 accumulators (8 values).
    auto gather4 = [&](uint4 cA, unsigned cB, f2& a0, f2& a1, f2& a2, f2& a3) {
#define TAP(c) { uint4 w = *(const uint4*)((const char*)s4 + ((unsigned)(c) << 4)); \
                 a0 += up2(w.x); a1 += up2(w.y); a2 += up2(w.z); a3 += up2(w.w); }
        TAP(cA.x & 0xffffu); TAP(cA.x >> 16);
        TAP(cA.y & 0xffffu); TAP(cA.y >> 16);
        TAP(cA.z & 0xffffu); TAP(cA.z >> 16);
        TAP(cA.w & 0xffffu); TAP(cA.w >> 16);
        TAP(cB);
#undef TAP
    };

    if (bid < 128) {
        // ------- lv1: (b, parity q, 4-ch group); 9216 positions -------
        const int q = (bid >> 2) & 1, c0 = (bid >> 3) * 4;
        const float* g0 = ref1 + (size_t)(b * 64 + c0) * 36864;

        for (int u2 = tid; u2 < 9216; u2 += 1024) {
            int ysh = u2 / 96, xsh = u2 - 96 * ysh;
            const float* gp = g0 + (size_t)(2 * ysh + q) * 192 + 2 * xsh;
            f2 v0 = ntload((const f2*)gp);
            f2 v1 = ntload((const f2*)(gp + 36864));
            f2 v2 = ntload((const f2*)(gp + 2 * 36864));
            f2 v3 = ntload((const f2*)(gp + 3 * 36864));
            uint4 w;
            w.x = cvt_pk_bf16(v0.x, v0.y); w.y = cvt_pk_bf16(v1.x, v1.y);
            w.z = cvt_pk_bf16(v2.x, v2.y); w.w = cvt_pk_bf16(v3.x, v3.y);
            *(uint4*)(s4 + 4 * u2) = w;
        }
        __syncthreads();

        float* ob = out + 4718592 + (size_t)(b * 64 + c0) * 36864;

        uint4 cA; unsigned cB;
        if (TAB) { cA = tA[tid]; cB = tB[tid]; }
        int u = tid;
#pragma unroll 2
        for (int k = 0; k < 9; ++k) {
            uint4 nA = cA; unsigned nB = cB;
            if (TAB && k < 8) { nA = tA[u + 1024]; nB = tB[u + 1024]; }
            if (!TAB) make_cells(u, cA, cB);
            f2 a0 = {0.f, 0.f}, a1 = {0.f, 0.f}, a2 = {0.f, 0.f}, a3 = {0.f, 0.f};
            gather4(cA, cB, a0, a1, a2, a3);
            a0 *= nv; a1 *= nv; a2 *= nv; a3 *= nv;
            int r = u / 96, t = u - 96 * r;
            float* op = ob + (size_t)(2 * r + q) * 192 + 2 * t;
            ntstore((f2*)op, a0);
            ntstore((f2*)(op + 36864), a1);
            ntstore((f2*)(op + 2 * 36864), a2);
            ntstore((f2*)(op + 3 * 36864), a3);
            u += 1024; cA = nA; cB = nB;
        }
    } else {
        // ------- lv2: (b, 8-ch group, pos half); 4608 positions -------
        const int r2 = bid - 128;
        const int grp = (r2 >> 2) & 15, h = (r2 >> 6) & 1;
        const int c0 = grp * 8;
        const float* g0 = ref2 + (size_t)(b * 128 + c0) * 9216;

        // Stage full 8-channel plane: 2 cells (2p, 2p+1) per iteration.
        for (int p = tid; p < 4608; p += 1024) {
            const float* gp = g0 + 2 * p;
            f2 v0 = ntload((const f2*)gp);
            f2 v1 = ntload((const f2*)(gp + 9216));
            f2 v2 = ntload((const f2*)(gp + 2 * 9216));
            f2 v3 = ntload((const f2*)(gp + 3 * 9216));
            f2 v4 = ntload((const f2*)(gp + 4 * 9216));
            f2 v5 = ntload((const f2*)(gp + 5 * 9216));
            f2 v6 = ntload((const f2*)(gp + 6 * 9216));
            f2 v7 = ntload((const f2*)(gp + 7 * 9216));
            uint4 wa, wb;
            wa.x = cvt_pk_bf16(v0.x, v1.x); wa.y = cvt_pk_bf16(v2.x, v3.x);
            wa.z = cvt_pk_bf16(v4.x, v5.x); wa.w = cvt_pk_bf16(v6.x, v7.x);
            wb.x = cvt_pk_bf16(v0.y, v1.y); wb.y = cvt_pk_bf16(v2.y, v3.y);
            wb.z = cvt_pk_bf16(v4.y, v5.y); wb.w = cvt_pk_bf16(v6.y, v7.y);
            *(uint4*)(s4 + 8 * p) = wa;
            *(uint4*)(s4 + 8 * p + 4) = wb;
        }
        __syncthreads();

        float* ob = out + (size_t)(b * 128 + c0) * 9216;
        const int u0 = h * 4608;

        auto do_pos = [&](int u, uint4 cA, unsigned cB) {
            f2 a0 = {0.f, 0.f}, a1 = {0.f, 0.f}, a2 = {0.f, 0.f}, a3 = {0.f, 0.f};
            gather4(cA, cB, a0, a1, a2, a3);
            a0 *= nv; a1 *= nv; a2 *= nv; a3 *= nv;
            float* op = ob + u;
            ntstore(op, a0.x);            ntstore(op + 9216, a0.y);
            ntstore(op + 2 * 9216, a1.x); ntstore(op + 3 * 9216, a1.y);
            ntstore(op + 4 * 9216, a2.x); ntstore(op + 5 * 9216, a2.y);
            ntstore(op + 6 * 9216, a3.x); ntstore(op + 7 * 9216, a3.y);
        };

        int u = u0 + tid;
        uint4 cA; unsigned cB;
        if (TAB) { cA = tA[u]; cB = tB[u]; }
#pragma unroll
        for (int k = 0; k < 4; ++k) {           // positions u0+tid+{0,1024,2048,3072}
            bool has_next = (k < 3) | (tid < 512);
            int un = has_next ? (u + 1024) : u;
            uint4 nA = cA; unsigned nB = cB;
            if (TAB) { nA = tA[un]; nB = tB[un]; }
            if (!TAB) make_cells(u, cA, cB);
            do_pos(u, cA, cB);
            u = un; cA = nA; cB = nB;
        }
        if (tid < 512) {                        // 5th position: u0+tid+4096
            if (!TAB) make_cells(u, cA, cB);
            do_pos(u, cA, cB);
        }
    }
}

extern "C" void kernel_launch(void* const* d_in, const int* in_sizes, int n_in,
                              void* d_out, int out_size, void* d_ws, size_t ws_size,
                              hipStream_t stream) {
    const int*   idx  = (const int*)d_in[0];   // R_lv2_star_arg [4,9216]
    const float* ref1 = (const float*)d_in[2]; // ref_lv1 [4,64,192,192]
    const float* ref2 = (const float*)d_in[3]; // ref_lv2 [4,128,96,96]
    float* outp = (float*)d_out;

    uint4* tabA = (uint4*)d_ws;                          // 4*9216*16 B
    unsigned short* tabB = (unsigned short*)((char*)d_ws + (size_t)4 * 9216 * 16);

    const size_t need = (size_t)4 * 9216 * 16 + (size_t)4 * 9216 * 2;  // 664 KB
    if (ws_size >= need) {
        hipLaunchKernelGGL(table_kernel, dim3(144), dim3(256), 0, stream,
                           idx, tabA, tabB);
        hipLaunchKernelGGL(transfer_kernel<true>, dim3(256), dim3(1024), 0, stream,
                           idx, ref1, ref2, tabA, tabB, outp);
    } else {
        hipLaunchKernelGGL(transfer_kernel<false>, dim3(256), dim3(1024), 0, stream,
                           idx, ref1, ref2, tabA, tabB, outp);
    }
}

// Round 14
// 27.681 us; speedup vs baseline: 1.1211x; 1.1211x over previous
//
#include <hip/hip_runtime.h>

// T_lv2: out[0..4718591]         = fold(gather(unfold(ref_lv2,3,1,1)))/9  [4,128,96,96]
// T_lv1: out[4718592..14155775]  = fold(gather(unfold(ref_lv1,6,2,2)))/9  [4,64,192,192]
//
// R14 = R10 restored exactly (best measured: 27.69us).
// Structure (empirically optimal after full sweep R7/R8/R9/R11/R13 all
// regressed): tap table as u16 cell indices (2 coalesced loads/position),
// 1-deep prefetch, unroll 2, bf16 4-value 8B cells, random ds_read_b64,
// 512 blocks x 512 thr, 73.75KB LDS (2 blocks/CU; natural bid mapping ->
// breadth-first pairs lv1+lv2 on each CU for stage/gather phase overlap).
// Staging pack via v_cvt_pk_bf16_f32 (RNE, 1 inst per pair).

typedef float f2 __attribute__((ext_vector_type(2)));
typedef float f4 __attribute__((ext_vector_type(4)));

#define NINE_INV (1.0f / 9.0f)
#define ZCELL 9216u

__device__ __forceinline__ unsigned cvt_pk_bf16(float a, float b) {
    unsigned r;
    asm("v_cvt_pk_bf16_f32 %0, %1, %2" : "=v"(r) : "v"(a), "v"(b));
    return r;   // lo16 = bf16(a), hi16 = bf16(b), RNE
}
__device__ __forceinline__ f2 up2(unsigned w) {
    f2 r;
    r.x = __builtin_bit_cast(float, w << 16);
    r.y = __builtin_bit_cast(float, w & 0xffff0000u);
    return r;
}
template <typename T> __device__ __forceinline__ T ntload(const T* p) {
    return __builtin_nontemporal_load(p);
}
template <typename T> __device__ __forceinline__ void ntstore(T* p, T v) {
    __builtin_nontemporal_store(v, p);
}

// Build the packed tap table: tabA[g] = taps 0..7 (8 x u16 cell idx), tabB[g] = tap 8.
__global__ __launch_bounds__(256) void table_kernel(
    const int* __restrict__ idx, uint4* __restrict__ tabA,
    unsigned short* __restrict__ tabB)
{
    int g = blockIdx.x * 256 + threadIdx.x;       // 0..36863
    int b = g / 9216;
    int u = g - b * 9216;
    const int* idxb = idx + b * 9216;
    int r = u / 96, t = u - 96 * r;
    unsigned e[9];
#pragma unroll
    for (int i = 0; i < 3; ++i) {
        int oy = r - 1 + i;
        bool oyv = (unsigned)oy < 96u;
#pragma unroll
        for (int j = 0; j < 3; ++j) {
            int ox = t - 1 + j;
            bool pv = oyv & ((unsigned)ox < 96u);
            int jv = idxb[pv ? oy * 96 + ox : 0];
            int jy = jv / 96, jx = jv - 96 * jy;
            int ysh = jy + 1 - i, xsh = jx + 1 - j;
            bool sv = pv & ((unsigned)ysh < 96u) & ((unsigned)xsh < 96u);
            e[i * 3 + j] = sv ? (unsigned)(ysh * 96 + xsh) : ZCELL;
        }
    }
    uint4 w;
    w.x = e[0] | (e[1] << 16);
    w.y = e[2] | (e[3] << 16);
    w.z = e[4] | (e[5] << 16);
    w.w = e[6] | (e[7] << 16);
    tabA[g] = w;
    tabB[g] = (unsigned short)e[8];
}

template <bool TAB>
__global__ __launch_bounds__(512, 4) void transfer_kernel(
    const int* __restrict__ idx,      // [4, 9216]
    const float* __restrict__ ref1,   // [4,64,192,192]
    const float* __restrict__ ref2,   // [4,128,96,96]
    const uint4* __restrict__ tabA,   // [4][9216] taps 0..7
    const unsigned short* __restrict__ tabB, // [4][9216] tap 8
    float* __restrict__ out)
{
    __shared__ __align__(16) unsigned s2[18436];   // 9217 cells x 2 words (+pad)
    const int tid = threadIdx.x;
    const int bid = blockIdx.x;
    const int b = bid & 3;

    if (tid < 4) s2[18432 + tid] = 0;              // zero cell (+pad)

    const uint4* tA = tabA + b * 9216;
    const unsigned short* tB = tabB + b * 9216;
    const int* idxb = idx + b * 9216;
    const f2 nv = {NINE_INV, NINE_INV};

    // inline fallback offset computation (cell index, ZCELL if invalid)
    auto inline_cells = [&](int u, unsigned* e) {
        int r = u / 96, t = u - 96 * r;
#pragma unroll
        for (int i = 0; i < 3; ++i) {
            int oy = r - 1 + i;
            bool oyv = (unsigned)oy < 96u;
#pragma unroll
            for (int j = 0; j < 3; ++j) {
                int ox = t - 1 + j;
                bool pv = oyv & ((unsigned)ox < 96u);
                int jv = idxb[pv ? oy * 96 + ox : 0];
                int jy = jv / 96, jx = jv - 96 * jy;
                int ysh = jy + 1 - i, xsh = jx + 1 - j;
                bool sv = pv & ((unsigned)ysh < 96u) & ((unsigned)xsh < 96u);
                e[i * 3 + j] = sv ? (unsigned)(ysh * 96 + xsh) : ZCELL;
            }
        }
    };

    auto do_taps = [&](const unsigned* cw, unsigned c8, f2& a0, f2& a1) {
#pragma unroll
        for (int q = 0; q < 4; ++q) {
            unsigned lo = cw[q] & 0xffffu, hi = cw[q] >> 16;
            uint2 wa = *(const uint2*)((const char*)s2 + (lo << 3));
            uint2 wb = *(const uint2*)((const char*)s2 + (hi << 3));
            a0 += up2(wa.x); a1 += up2(wa.y);
            a0 += up2(wb.x); a1 += up2(wb.y);
        }
        uint2 wc = *(const uint2*)((const char*)s2 + (c8 << 3));
        a0 += up2(wc.x); a1 += up2(wc.y);
    };

    if (bid < 256) {
        // ---------------- lv1: b, parity q, channel pair ----------------
        const int q = (bid >> 2) & 1, c0 = (bid >> 3) * 2;
        const float* g0 = ref1 + (size_t)(b * 64 + c0) * 36864;

        for (int u2 = tid; u2 < 4608; u2 += 512) {
            int ysh = u2 / 48, xsh0 = 2 * (u2 - 48 * ysh);
            const float* gp = g0 + (size_t)(2 * ysh + q) * 192 + 2 * xsh0;
            f4 va = ntload((const f4*)gp);            // ch0
            f4 vb = ntload((const f4*)(gp + 36864));  // ch1
            uint4 w;
            w.x = cvt_pk_bf16(va.x, va.y); w.y = cvt_pk_bf16(vb.x, vb.y);
            w.z = cvt_pk_bf16(va.z, va.w); w.w = cvt_pk_bf16(vb.z, vb.w);
            *(uint4*)(s2 + 4 * u2) = w;
        }
        __syncthreads();

        float* ob = out + 4718592 + (size_t)(b * 64 + c0) * 36864;

        uint4 cA; unsigned cB;
        if (TAB) { cA = tA[tid]; cB = tB[tid]; }
        int u = tid;
#pragma unroll 2
        for (int k = 0; k < 18; ++k) {
            uint4 nA = cA; unsigned nB = cB;
            if (TAB && k < 17) { nA = tA[u + 512]; nB = tB[u + 512]; }
            unsigned cw[4];
            unsigned c8;
            if (TAB) {
                cw[0] = cA.x; cw[1] = cA.y; cw[2] = cA.z; cw[3] = cA.w; c8 = cB;
            } else {
                unsigned e[9];
                inline_cells(u, e);
                cw[0] = e[0] | (e[1] << 16); cw[1] = e[2] | (e[3] << 16);
                cw[2] = e[4] | (e[5] << 16); cw[3] = e[6] | (e[7] << 16);
                c8 = e[8];
            }
            f2 a0 = {0.f, 0.f}, a1 = {0.f, 0.f};
            do_taps(cw, c8, a0, a1);
            a0 *= nv; a1 *= nv;
            int r = u / 96, t = u - 96 * r;
            float* op = ob + (size_t)(2 * r + q) * 192 + 2 * t;
            ntstore((f2*)op, a0);
            ntstore((f2*)(op + 36864), a1);
            u += 512; cA = nA; cB = nB;
        }
    } else {
        // ---------------- lv2: b, 4-ch group, position half ----------------
        const int r2 = bid - 256;
        const int grp = (r2 >> 2) & 31, h = (r2 >> 7) & 1;
        const int c0 = grp * 4;
        const float* g0 = ref2 + (size_t)(b * 128 + c0) * 9216;

        for (int u2 = tid; u2 < 4608; u2 += 512) {
            f2 p0 = ntload((const f2*)(g0 + 2 * u2));
            f2 p1 = ntload((const f2*)(g0 + 9216 + 2 * u2));
            f2 p2 = ntload((const f2*)(g0 + 2 * 9216 + 2 * u2));
            f2 p3 = ntload((const f2*)(g0 + 3 * 9216 + 2 * u2));
            uint4 w;
            w.x = cvt_pk_bf16(p0.x, p1.x); w.y = cvt_pk_bf16(p2.x, p3.x);
            w.z = cvt_pk_bf16(p0.y, p1.y); w.w = cvt_pk_bf16(p2.y, p3.y);
            *(uint4*)(s2 + 4 * u2) = w;
        }
        __syncthreads();

        float* ob = out + (size_t)(b * 128 + c0) * 9216;

        const int u0 = h * 4608;
        uint4 cA; unsigned cB;
        if (TAB) { cA = tA[u0 + tid]; cB = tB[u0 + tid]; }
        int u = u0 + tid;
#pragma unroll 2
        for (int k = 0; k < 9; ++k) {
            uint4 nA = cA; unsigned nB = cB;
            if (TAB && k < 8) { nA = tA[u + 512]; nB = tB[u + 512]; }
            unsigned cw[4];
            unsigned c8;
            if (TAB) {
                cw[0] = cA.x; cw[1] = cA.y; cw[2] = cA.z; cw[3] = cA.w; c8 = cB;
            } else {
                unsigned e[9];
                inline_cells(u, e);
                cw[0] = e[0] | (e[1] << 16); cw[1] = e[2] | (e[3] << 16);
                cw[2] = e[4] | (e[5] << 16); cw[3] = e[6] | (e[7] << 16);
                c8 = e[8];
            }
            f2 a0 = {0.f, 0.f}, a1 = {0.f, 0.f};
            do_taps(cw, c8, a0, a1);
            a0 *= nv; a1 *= nv;
            float* op = ob + u;
            ntstore(op, a0.x);            ntstore(op + 9216, a0.y);
            ntstore(op + 2 * 9216, a1.x); ntstore(op + 3 * 9216, a1.y);
            u += 512; cA = nA; cB = nB;
        }
    }
}

extern "C" void kernel_launch(void* const* d_in, const int* in_sizes, int n_in,
                              void* d_out, int out_size, void* d_ws, size_t ws_size,
                              hipStream_t stream) {
    const int*   idx  = (const int*)d_in[0];   // R_lv2_star_arg [4,9216]
    const float* ref1 = (const float*)d_in[2]; // ref_lv1 [4,64,192,192]
    const float* ref2 = (const float*)d_in[3]; // ref_lv2 [4,128,96,96]
    float* outp = (float*)d_out;

    uint4* tabA = (uint4*)d_ws;                          // 4*9216*16 B
    unsigned short* tabB = (unsigned short*)((char*)d_ws + (size_t)4 * 9216 * 16);

    const size_t need = (size_t)4 * 9216 * 16 + (size_t)4 * 9216 * 2;  // 664 KB
    if (ws_size >= need) {
        hipLaunchKernelGGL(table_kernel, dim3(144), dim3(256), 0, stream,
                           idx, tabA, tabB);
        hipLaunchKernelGGL(transfer_kernel<true>, dim3(512), dim3(512), 0, stream,
                           idx, ref1, ref2, tabA, tabB, outp);
    } else {
        hipLaunchKernelGGL(transfer_kernel<false>, dim3(512), dim3(512), 0, stream,
                           idx, ref1, ref2, tabA, tabB, outp);
    }
}